// Round 6
// baseline (1059.431 us; speedup 1.0000x reference)
//
#include <hip/hip_runtime.h>
#include <hip/hip_fp16.h>

// Problem constants (fixed by setup_inputs)
#define E_TOTAL 524288
#define RRELU_SLOPE 0.22916666666666666f

typedef float f32x4 __attribute__((ext_vector_type(4)));
typedef short short8_t __attribute__((ext_vector_type(8)));

__device__ inline unsigned short f2bf(float x) {
  unsigned int u = __float_as_uint(x);
  u += 0x7FFFu + ((u >> 16) & 1u);   // RNE
  return (unsigned short)(u >> 16);
}

__device__ inline float bf16f(unsigned short u) {
  return __builtin_bit_cast(float, ((unsigned int)u) << 16);
}

__device__ inline float dot4(float4 a, float4 b) {
  return a.x * b.x + a.y * b.y + a.z * b.z + a.w * b.w;
}

// ---------------------------------------------------------------------------
// Generic bf16-MFMA GEMM, dual parameter set selected by blockIdx.z.
// C[M,N] = act(A[M,K](fp32) @ B[K,N] + bias); BT[N][K] bf16.
// Grid: (M/128, N/128, 2). act: 0=none, 2=rrelu
// ---------------------------------------------------------------------------
__global__ __launch_bounds__(256) void gemm_bf16_dual(
    const float* __restrict__ A1, const unsigned short* __restrict__ BT1,
    const float* __restrict__ bias1, float* __restrict__ C1,
    const float* __restrict__ A2, const unsigned short* __restrict__ BT2,
    const float* __restrict__ bias2, float* __restrict__ C2,
    int lda, int ldc, int K, int act)
{
  const float* A = blockIdx.z ? A2 : A1;
  const unsigned short* BT = blockIdx.z ? BT2 : BT1;
  const float* bias = blockIdx.z ? bias2 : bias1;
  float* C = blockIdx.z ? C2 : C1;

  __shared__ unsigned short As[128][32];
  __shared__ unsigned short Bs[128][32];
  const int tid = threadIdx.x;
  const int bm = blockIdx.x, bn = blockIdx.y;
  const int w = tid >> 6, l = tid & 63;
  const int wm = (w & 1) * 64, wn = (w >> 1) * 64;
  const int q = l >> 4, r = l & 15;

  f32x4 acc[4][4];
  for (int i = 0; i < 4; ++i)
    for (int j = 0; j < 4; ++j)
      acc[i][j] = (f32x4){0.f, 0.f, 0.f, 0.f};

  const int sm = tid >> 1;
  const int sk = (tid & 1) * 16;
  const float* ap = A + (size_t)(bm * 128 + sm) * lda + sk;
  const unsigned short* bp = BT + (size_t)(bn * 128 + sm) * K + sk;

  for (int k0 = 0; k0 < K; k0 += 32) {
    float4 f0 = *(const float4*)(ap + k0);
    float4 f1 = *(const float4*)(ap + k0 + 4);
    float4 f2 = *(const float4*)(ap + k0 + 8);
    float4 f3 = *(const float4*)(ap + k0 + 12);
    uint4 p0, p1;
    p0.x = (unsigned)f2bf(f0.x) | ((unsigned)f2bf(f0.y) << 16);
    p0.y = (unsigned)f2bf(f0.z) | ((unsigned)f2bf(f0.w) << 16);
    p0.z = (unsigned)f2bf(f1.x) | ((unsigned)f2bf(f1.y) << 16);
    p0.w = (unsigned)f2bf(f1.z) | ((unsigned)f2bf(f1.w) << 16);
    p1.x = (unsigned)f2bf(f2.x) | ((unsigned)f2bf(f2.y) << 16);
    p1.y = (unsigned)f2bf(f2.z) | ((unsigned)f2bf(f2.w) << 16);
    p1.z = (unsigned)f2bf(f3.x) | ((unsigned)f2bf(f3.y) << 16);
    p1.w = (unsigned)f2bf(f3.z) | ((unsigned)f2bf(f3.w) << 16);
    *(uint4*)&As[sm][sk] = p0;
    *(uint4*)&As[sm][sk + 8] = p1;
    uint4 b0 = *(const uint4*)(bp + k0);
    uint4 b1 = *(const uint4*)(bp + k0 + 8);
    *(uint4*)&Bs[sm][sk] = b0;
    *(uint4*)&Bs[sm][sk + 8] = b1;
    __syncthreads();

    short8_t af[4], bfr[4];
    for (int mt = 0; mt < 4; ++mt)
      af[mt] = *(const short8_t*)&As[wm + mt * 16 + r][q * 8];
    for (int nt = 0; nt < 4; ++nt)
      bfr[nt] = *(const short8_t*)&Bs[wn + nt * 16 + r][q * 8];
    for (int mt = 0; mt < 4; ++mt)
      for (int nt = 0; nt < 4; ++nt)
        acc[mt][nt] = __builtin_amdgcn_mfma_f32_16x16x32_bf16(
            af[mt], bfr[nt], acc[mt][nt], 0, 0, 0);
    __syncthreads();
  }

  for (int nt = 0; nt < 4; ++nt) {
    int gc = bn * 128 + wn + nt * 16 + r;
    float bv = bias ? bias[gc] : 0.f;
    for (int mt = 0; mt < 4; ++mt) {
      int gm = bm * 128 + wm + mt * 16 + q * 4;
      for (int rr = 0; rr < 4; ++rr) {
        float v = acc[mt][nt][rr] + bv;
        if (act == 2) v = (v >= 0.f) ? v : v * RRELU_SLOPE;
        C[(size_t)(gm + rr) * ldc + gc] = v;
      }
    }
  }
}

// ---------------------------------------------------------------------------
// Per-graph counting sort of edges by destination node (dual-mol grid 512).
// meta[p] = src | dst<<8 (dst non-decreasing), perm[p] = original local idx.
// ---------------------------------------------------------------------------
__global__ __launch_bounds__(256) void sort_edges_dual(
    const int* __restrict__ ei1, const int* __restrict__ ei2,
    int* __restrict__ meta1, int* __restrict__ meta2,
    int* __restrict__ perm1, int* __restrict__ perm2)
{
  const int mol = blockIdx.x >> 8;
  const int g = blockIdx.x & 255;
  const int* eidx = mol ? ei2 : ei1;
  int* meta = mol ? meta2 : meta1;
  int* perm = mol ? perm2 : perm1;

  __shared__ int cnt[4][64];
  __shared__ int startS[65];
  __shared__ int cur[64];
  const int t = threadIdx.x, w = t >> 6;
  cnt[w][t & 63] = 0;
  if (t < 64) cur[t] = 0;
  __syncthreads();
  for (int i = t; i < 2048; i += 256)
    atomicAdd(&cnt[w][eidx[E_TOTAL + g * 2048 + i] & 63], 1);
  __syncthreads();
  if (t == 0) {
    int acc = 0;
    for (int n = 0; n < 64; ++n) {
      startS[n] = acc;
      acc += cnt[0][n] + cnt[1][n] + cnt[2][n] + cnt[3][n];
    }
    startS[64] = acc;
  }
  __syncthreads();
  for (int i = t; i < 2048; i += 256) {
    int s = eidx[g * 2048 + i] & 63;
    int d = eidx[E_TOTAL + g * 2048 + i] & 63;
    int p = startS[d] + atomicAdd(&cur[d], 1);
    meta[g * 2048 + p] = s | (d << 8);
    perm[g * 2048 + p] = i;
  }
}

// ---------------------------------------------------------------------------
// Gather ea through sort permutation, convert fp32 -> bf16 [E][16] (sorted).
// Dual, grid 4096 x 256, one thread per sorted edge.
// ---------------------------------------------------------------------------
__global__ __launch_bounds__(256) void ea_gather_pack_dual(
    const float* __restrict__ ea1, const float* __restrict__ ea2,
    const int* __restrict__ perm1, const int* __restrict__ perm2,
    unsigned short* __restrict__ o1, unsigned short* __restrict__ o2)
{
  const int mol = blockIdx.x >> 11;
  const float* ea = mol ? ea2 : ea1;
  const int* perm = mol ? perm2 : perm1;
  unsigned short* out = mol ? o2 : o1;
  int p = (blockIdx.x & 2047) * 256 + threadIdx.x;  // 0..E-1
  int g = p >> 11;
  int i = perm[p];
  const float* s = ea + (size_t)(g * 2048 + i) * 16;
  float4 v0 = *(const float4*)(s);
  float4 v1 = *(const float4*)(s + 4);
  float4 v2 = *(const float4*)(s + 8);
  float4 v3 = *(const float4*)(s + 12);
  uint4 q0, q1;
  q0.x = (unsigned)f2bf(v0.x) | ((unsigned)f2bf(v0.y) << 16);
  q0.y = (unsigned)f2bf(v0.z) | ((unsigned)f2bf(v0.w) << 16);
  q0.z = (unsigned)f2bf(v1.x) | ((unsigned)f2bf(v1.y) << 16);
  q0.w = (unsigned)f2bf(v1.z) | ((unsigned)f2bf(v1.w) << 16);
  q1.x = (unsigned)f2bf(v2.x) | ((unsigned)f2bf(v2.y) << 16);
  q1.y = (unsigned)f2bf(v2.z) | ((unsigned)f2bf(v2.w) << 16);
  q1.z = (unsigned)f2bf(v3.x) | ((unsigned)f2bf(v3.y) << 16);
  q1.w = (unsigned)f2bf(v3.z) | ((unsigned)f2bf(v3.w) << 16);
  *(uint4*)(out + (size_t)p * 16) = q0;
  *(uint4*)(out + (size_t)p * 16 + 8) = q1;
}

// ---------------------------------------------------------------------------
// Edge conv v6 — MFMA path. Per block: (graph, dim-half), 512 thr / 8 waves.
// Per 128-edge chunk c:
//   phase1: stage meta[128] (sorted src|dst<<8) into LDS
//   phase2: wave w owns edges [w*16, w*16+16):
//     T = ea_chunk @ We via mfma_16x16x32 (K=16 real, q>=2 frags zero;
//         We B-frags preloaded to registers from global webt[half][d][k]).
//     P[e][d] = bf16(relu(T + ypk[src_e][d])) -> LDS PT[d][e] (stride 136)
//   phase3: wave w owns dims [w*16, w*16+16):
//     acc[mt] += S_frag @ P  where S[n][e] = (dst_e==n) built IN REGISTERS
//     by comparing dst (from meta) to mt*16+r; dst-sorted => only 1-2 active
//     mt tiles per chunk. agg never leaves MFMA accumulators.
// Epilogue: acc -> LDS (reuse PT) -> coalesced relu(y_self + agg) store.
// LDS: PT 34816 + ypk 16896 + meta 512 = 52224 B -> 2+ blocks/CU.
// ---------------------------------------------------------------------------
__global__ __launch_bounds__(512, 4) void edge_conv_dual(
    const float* __restrict__ y1, const int* __restrict__ meta1,
    const unsigned short* __restrict__ eab1, const unsigned short* __restrict__ webt1,
    float* __restrict__ xo1,
    const float* __restrict__ y2, const int* __restrict__ meta2,
    const unsigned short* __restrict__ eab2, const unsigned short* __restrict__ webt2,
    float* __restrict__ xo2)
{
  const float* y; const int* meta; const unsigned short* eab;
  const unsigned short* webt; float* xo;
  if (blockIdx.z == 0) { y = y1; meta = meta1; eab = eab1; webt = webt1; xo = xo1; }
  else                 { y = y2; meta = meta2; eab = eab2; webt = webt2; xo = xo2; }

  __shared__ __align__(16) unsigned char smem[52224];
  unsigned short* PT  = (unsigned short*)(smem);           // [128 dims][136] bf16
  unsigned short* ypk = (unsigned short*)(smem + 34816);   // [64 nodes][132] bf16
  int* metal          = (int*)(smem + 51712);              // [128]
  float* aggf         = (float*)(smem);                    // reuse PT region

  const int g = blockIdx.x >> 1;
  const int hlf = blockIdx.x & 1;
  const int dbase = hlf * 128;
  const int tid = threadIdx.x;
  const int w = tid >> 6, l = tid & 63;
  const int q = l >> 4, r = l & 15;

  // stage y msg-half as bf16 [64][132]
  for (int i = tid; i < 8192; i += 512) {
    int n = i >> 7, d = i & 127;
    ypk[n * 132 + d] = f2bf(y[(size_t)(g * 64 + n) * 512 + dbase + d]);
  }

  // We B-frags to registers (once per block). B[k][n=d]: lane q<2 real, else 0.
  short8_t webf[8];
#pragma unroll
  for (int nd = 0; nd < 8; ++nd) {
    short8_t z = {};
    if (q < 2)
      z = *(const short8_t*)(webt + ((size_t)hlf * 128 + nd * 16 + r) * 16 + q * 8);
    webf[nd] = z;
  }

  f32x4 acc[4];
#pragma unroll
  for (int i = 0; i < 4; ++i) acc[i] = (f32x4){0.f, 0.f, 0.f, 0.f};

  const int ebase = g * 2048;
  const unsigned sONE = 0x3F80u;  // bf16 1.0
  __syncthreads();

  for (int c = 0; c < 16; ++c) {
    const int cb = c * 128;
    // a-frag ea for this wave's 16 edges, straight from global (L2/L3-hot)
    short8_t af = {};
    if (q < 2)
      af = *(const short8_t*)(eab + ((size_t)(ebase + cb + w * 16 + r)) * 16 + q * 8);
    // phase 1: stage meta
    if (tid < 128) metal[tid] = meta[ebase + cb + tid];
    __syncthreads();

    // phase 2: T = ea@We (rows e = w*16+q*4+rr, cols d = nd*16+r), P -> LDS
    int4 mv = *(const int4*)(metal + w * 16 + q * 4);
    const int s0 = mv.x & 63, s1 = mv.y & 63, s2 = mv.z & 63, s3 = mv.w & 63;
#pragma unroll
    for (int nd = 0; nd < 8; ++nd) {
      f32x4 t = (f32x4){0.f, 0.f, 0.f, 0.f};
      t = __builtin_amdgcn_mfma_f32_16x16x32_bf16(af, webf[nd], t, 0, 0, 0);
      const int d = nd * 16 + r;
      float v0 = fmaxf(t[0] + bf16f(ypk[s0 * 132 + d]), 0.f);
      float v1 = fmaxf(t[1] + bf16f(ypk[s1 * 132 + d]), 0.f);
      float v2 = fmaxf(t[2] + bf16f(ypk[s2 * 132 + d]), 0.f);
      float v3 = fmaxf(t[3] + bf16f(ypk[s3 * 132 + d]), 0.f);
      unsigned p01 = (unsigned)f2bf(v0) | ((unsigned)f2bf(v1) << 16);
      unsigned p23 = (unsigned)f2bf(v2) | ((unsigned)f2bf(v3) << 16);
      uint2 pk; pk.x = p01; pk.y = p23;
      *(uint2*)(PT + (size_t)d * 136 + w * 16 + q * 4) = pk;
    }
    __syncthreads();

    // phase 3: acc[mt] += S @ P ; S-frags built in registers from dst
    int mtlo = __builtin_amdgcn_readfirstlane(metal[0] >> 8) >> 4;
    int mthi = __builtin_amdgcn_readfirstlane(metal[127] >> 8) >> 4;
#pragma unroll
    for (int kk = 0; kk < 4; ++kk) {
      int4 ma = *(const int4*)(metal + kk * 32 + q * 8);
      int4 mb = *(const int4*)(metal + kk * 32 + q * 8 + 4);
      short8_t pb = *(const short8_t*)(PT + (size_t)(w * 16 + r) * 136 + kk * 32 + q * 8);
      const int d0 = ma.x >> 8, d1 = ma.y >> 8, d2 = ma.z >> 8, d3 = ma.w >> 8;
      const int d4 = mb.x >> 8, d5 = mb.y >> 8, d6 = mb.z >> 8, d7 = mb.w >> 8;
#pragma unroll
      for (int mt = 0; mt < 4; ++mt) {
        if (mt < mtlo || mt > mthi) continue;
        const int tgt = mt * 16 + r;
        union { unsigned u[4]; short8_t v; } sa;
        sa.u[0] = (d0 == tgt ? sONE : 0u) | ((d1 == tgt ? sONE : 0u) << 16);
        sa.u[1] = (d2 == tgt ? sONE : 0u) | ((d3 == tgt ? sONE : 0u) << 16);
        sa.u[2] = (d4 == tgt ? sONE : 0u) | ((d5 == tgt ? sONE : 0u) << 16);
        sa.u[3] = (d6 == tgt ? sONE : 0u) | ((d7 == tgt ? sONE : 0u) << 16);
        acc[mt] = __builtin_amdgcn_mfma_f32_16x16x32_bf16(sa.v, pb, acc[mt], 0, 0, 0);
      }
    }
    __syncthreads();
  }

  // acc -> aggf (node = mt*16+q*4+rr, d = w*16+r)
#pragma unroll
  for (int mt = 0; mt < 4; ++mt)
#pragma unroll
    for (int rr = 0; rr < 4; ++rr)
      aggf[(mt * 16 + q * 4 + rr) * 128 + w * 16 + r] = acc[mt][rr];
  __syncthreads();
  for (int i = tid; i < 8192; i += 512) {
    int n = i >> 7, dd = i & 127;
    float v = y[(size_t)(g * 64 + n) * 512 + 256 + dbase + dd] + aggf[i];
    xo[(size_t)(g * 64 + n) * 256 + dbase + dd] = fmaxf(v, 0.f);
  }
}

// ---------------------------------------------------------------------------
// dot_pool: per graph, item = X1 @ X2^T [64x64]; write max & mean to fusion.
// ---------------------------------------------------------------------------
__global__ __launch_bounds__(256) void dot_pool_k(
    const float* __restrict__ x1, const float* __restrict__ x2,
    float* __restrict__ fusion, int step)
{
  __shared__ float s1[64][68];
  __shared__ float s2[64][68];
  __shared__ float redm[4], reds[4];
  const int g = blockIdx.x;
  const int tid = threadIdx.x;
  const int ti = (tid & 15) * 4;
  const int tj = (tid >> 4) * 4;
  float acc[4][4] = {};
  for (int kc = 0; kc < 256; kc += 64) {
    for (int rr = 0; rr < 4; ++rr) {
      int lin = tid + rr * 256;
      int n = lin >> 4, k4 = (lin & 15) * 4;
      *(float4*)&s1[n][k4] = *(const float4*)(x1 + (size_t)(g * 64 + n) * 256 + kc + k4);
      *(float4*)&s2[n][k4] = *(const float4*)(x2 + (size_t)(g * 64 + n) * 256 + kc + k4);
    }
    __syncthreads();
    for (int kk = 0; kk < 64; kk += 4) {
      float4 a0 = *(const float4*)&s1[ti + 0][kk];
      float4 a1 = *(const float4*)&s1[ti + 1][kk];
      float4 a2 = *(const float4*)&s1[ti + 2][kk];
      float4 a3 = *(const float4*)&s1[ti + 3][kk];
      float4 b0 = *(const float4*)&s2[tj + 0][kk];
      float4 b1 = *(const float4*)&s2[tj + 1][kk];
      float4 b2 = *(const float4*)&s2[tj + 2][kk];
      float4 b3 = *(const float4*)&s2[tj + 3][kk];
      acc[0][0] += dot4(a0, b0); acc[0][1] += dot4(a0, b1);
      acc[0][2] += dot4(a0, b2); acc[0][3] += dot4(a0, b3);
      acc[1][0] += dot4(a1, b0); acc[1][1] += dot4(a1, b1);
      acc[1][2] += dot4(a1, b2); acc[1][3] += dot4(a1, b3);
      acc[2][0] += dot4(a2, b0); acc[2][1] += dot4(a2, b1);
      acc[2][2] += dot4(a2, b2); acc[2][3] += dot4(a2, b3);
      acc[3][0] += dot4(a3, b0); acc[3][1] += dot4(a3, b1);
      acc[3][2] += dot4(a3, b2); acc[3][3] += dot4(a3, b3);
    }
    __syncthreads();
  }
  float mymax = -1e30f, mysum = 0.f;
  for (int i = 0; i < 4; ++i)
    for (int j = 0; j < 4; ++j) {
      mymax = fmaxf(mymax, acc[i][j]);
      mysum += acc[i][j];
    }
  for (int off = 32; off; off >>= 1) {
    mymax = fmaxf(mymax, __shfl_down(mymax, off, 64));
    mysum += __shfl_down(mysum, off, 64);
  }
  if ((tid & 63) == 0) { redm[tid >> 6] = mymax; reds[tid >> 6] = mysum; }
  __syncthreads();
  if (tid == 0) {
    float gm = fmaxf(fmaxf(redm[0], redm[1]), fmaxf(redm[2], redm[3]));
    float gs = reds[0] + reds[1] + reds[2] + reds[3];
    fusion[g * 6 + step * 2] = gm;
    fusion[g * 6 + step * 2 + 1] = gs * (1.f / 4096.f);
  }
}

// ---------------------------------------------------------------------------
// readout (dual, grid 512): R[g] = [mean | sum | top3-by-last-col rows]
// ---------------------------------------------------------------------------
__global__ __launch_bounds__(256) void readout_dual(
    const float* __restrict__ xm1, const float* __restrict__ xm2,
    float* __restrict__ R1, float* __restrict__ R2)
{
  const int mol = blockIdx.x >> 8;
  const float* xm = mol ? xm2 : xm1;
  float* R = mol ? R2 : R1;
  __shared__ float lastcol[64];
  __shared__ int topi[3];
  const int g = blockIdx.x & 255, d = threadIdx.x;
  float s = 0.f;
  for (int n = 0; n < 64; ++n) s += xm[(size_t)(g * 64 + n) * 256 + d];
  R[(size_t)g * 1280 + d] = s * (1.f / 64.f);
  R[(size_t)g * 1280 + 256 + d] = s;
  if (d < 64) lastcol[d] = xm[(size_t)(g * 64 + d) * 256 + 255];
  __syncthreads();
  if (d == 0) {
    unsigned long long used = 0;
    for (int j = 0; j < 3; ++j) {
      float best = -1e30f;
      int bi = 0;
      for (int n = 0; n < 64; ++n) {
        if ((used >> n) & 1ull) continue;
        if (lastcol[n] > best) { best = lastcol[n]; bi = n; }
      }
      used |= (1ull << bi);
      topi[j] = bi;
    }
  }
  __syncthreads();
  for (int j = 0; j < 3; ++j)
    R[(size_t)g * 1280 + 512 + j * 256 + d] =
        xm[(size_t)(g * 64 + topi[j]) * 256 + d];
}

// ---------------------------------------------------------------------------
// final head: out = (cat(outm1, outm2, fusion) @ Wo1 + bo1) @ Wo2 + bo2
// ---------------------------------------------------------------------------
__global__ __launch_bounds__(256) void final_head(
    const float* __restrict__ outm1, const float* __restrict__ outm2,
    const float* __restrict__ fusion,
    const float* __restrict__ Wo1, const float* __restrict__ bo1,
    const float* __restrict__ Wo2, const float* __restrict__ bo2,
    float* __restrict__ out)
{
  __shared__ float cat[520];
  __shared__ float r0s[4], r1s[4];
  const int g = blockIdx.x, t = threadIdx.x;
  cat[t] = outm1[(size_t)g * 256 + t];
  cat[256 + t] = outm2[(size_t)g * 256 + t];
  if (t < 6) cat[512 + t] = fusion[g * 6 + t];
  __syncthreads();
  float acc = bo1[t];
  for (int k = 0; k < 518; ++k) acc = fmaf(cat[k], Wo1[(size_t)k * 256 + t], acc);
  float p0 = acc * Wo2[t * 2];
  float p1 = acc * Wo2[t * 2 + 1];
  for (int off = 32; off; off >>= 1) {
    p0 += __shfl_down(p0, off, 64);
    p1 += __shfl_down(p1, off, 64);
  }
  if ((t & 63) == 0) { r0s[t >> 6] = p0; r1s[t >> 6] = p1; }
  __syncthreads();
  if (t == 0) {
    out[g * 2] = r0s[0] + r0s[1] + r0s[2] + r0s[3] + bo2[0];
    out[g * 2 + 1] = r1s[0] + r1s[1] + r1s[2] + r1s[3] + bo2[1];
  }
}

// ---------------------------------------------------------------------------
// All weight transposes in one launch (ranges as before).
// ---------------------------------------------------------------------------
__global__ __launch_bounds__(256) void transpose_all(
    const float* __restrict__ W0_1, const float* __restrict__ W0_2,
    const float* __restrict__ Wn1, const float* __restrict__ Ws1,
    const float* __restrict__ Wn2, const float* __restrict__ Ws2,
    const float* __restrict__ Wf1, const float* __restrict__ Wf2,
    unsigned short* __restrict__ W0T1, unsigned short* __restrict__ W0T2,
    unsigned short* __restrict__ WcT1, unsigned short* __restrict__ WcT2,
    unsigned short* __restrict__ WfT1, unsigned short* __restrict__ WfT2)
{
  const int b = blockIdx.x, n = threadIdx.x;
  const float* src;
  unsigned short* dst;
  int k, K;
  if (b < 128)       { src = W0_1; dst = W0T1;        k = b;        K = 128; }
  else if (b < 256)  { src = W0_2; dst = W0T2;        k = b - 128;  K = 128; }
  else if (b < 512)  { src = Wn1;  dst = WcT1;        k = b - 256;  K = 256; }
  else if (b < 768)  { src = Ws1;  dst = WcT1 + 65536;k = b - 512;  K = 256; }
  else if (b < 1024) { src = Wn2;  dst = WcT2;        k = b - 768;  K = 256; }
  else if (b < 1280) { src = Ws2;  dst = WcT2 + 65536;k = b - 1024; K = 256; }
  else if (b < 2560) { src = Wf1;  dst = WfT1;        k = b - 1280; K = 1280; }
  else               { src = Wf2;  dst = WfT2;        k = b - 2560; K = 1280; }
  dst[n * K + k] = f2bf(src[(size_t)k * 256 + n]);
}

// ---------------------------------------------------------------------------
// bcat (bm|bs) + webt: [half][d 0..127][k 0..15] bf16 = We[k][half*128+d]
// grid 36 x 256 -> 9216: [0,512) bcat1 | [512,1024) bcat2 |
// [1024,5120) webt1 | [5120,9216) webt2
// ---------------------------------------------------------------------------
__global__ void misc_prep(
    const float* bm1, const float* bs1, const float* bm2, const float* bs2,
    const float* We1, const float* We2,
    float* bcat1, float* bcat2,
    unsigned short* webt1, unsigned short* webt2)
{
  int idx = blockIdx.x * 256 + threadIdx.x;
  if (idx < 512) {
    bcat1[idx] = idx < 256 ? bm1[idx] : bs1[idx - 256];
  } else if (idx < 1024) {
    int i = idx - 512;
    bcat2[i] = i < 256 ? bm2[i] : bs2[i - 256];
  } else if (idx < 5120) {
    int i = idx - 1024;            // [h][d][k]
    int h = i >> 11, rem = i & 2047, d = rem >> 4, k = rem & 15;
    webt1[i] = f2bf(We1[(size_t)k * 256 + h * 128 + d]);
  } else if (idx < 9216) {
    int i = idx - 5120;
    int h = i >> 11, rem = i & 2047, d = rem >> 4, k = rem & 15;
    webt2[i] = f2bf(We2[(size_t)k * 256 + h * 128 + d]);
  }
}

// ---------------------------------------------------------------------------
extern "C" void kernel_launch(void* const* d_in, const int* in_sizes, int n_in,
                              void* d_out, int out_size, void* d_ws, size_t ws_size,
                              hipStream_t stream)
{
  const float* x1 = (const float*)d_in[0];
  const int* ei1 = (const int*)d_in[1];
  const float* ea1 = (const float*)d_in[2];
  const float* x2 = (const float*)d_in[4];
  const int* ei2 = (const int*)d_in[5];
  const float* ea2 = (const float*)d_in[6];
  const float* W0_1 = (const float*)d_in[8];
  const float* b0_1 = (const float*)d_in[9];
  const float* W0_2 = (const float*)d_in[10];
  const float* b0_2 = (const float*)d_in[11];
  const float* Wn1 = (const float*)d_in[12];
  const float* We1 = (const float*)d_in[13];
  const float* bm1 = (const float*)d_in[14];
  const float* Ws1 = (const float*)d_in[15];
  const float* bs1 = (const float*)d_in[16];
  const float* Wn2 = (const float*)d_in[17];
  const float* We2 = (const float*)d_in[18];
  const float* bm2 = (const float*)d_in[19];
  const float* Ws2 = (const float*)d_in[20];
  const float* bs2 = (const float*)d_in[21];
  const float* Wf1 = (const float*)d_in[22];
  const float* bf1 = (const float*)d_in[23];
  const float* Wf2 = (const float*)d_in[24];
  const float* bf2 = (const float*)d_in[25];
  const float* Wo1 = (const float*)d_in[26];
  const float* bo1 = (const float*)d_in[27];
  const float* Wo2 = (const float*)d_in[28];
  const float* bo2 = (const float*)d_in[29];
  float* out = (float*)d_out;

  float* w = (float*)d_ws;
  size_t off = 0;
  auto alloc = [&](size_t nf) { float* p = w + off; off += nf; return p; };
  float* xmA1 = alloc(4194304);
  float* xmA2 = alloc(4194304);
  float* xmB1 = alloc(4194304);
  float* xmB2 = alloc(4194304);
  float* y1 = alloc(8388608);
  float* y2 = alloc(8388608);
  float* R1 = alloc(327680);
  float* R2 = alloc(327680);
  float* outm1 = alloc(65536);
  float* outm2 = alloc(65536);
  float* fusion = alloc(1536);
  float* bcat1 = alloc(512);
  float* bcat2 = alloc(512);
  unsigned short* W0T1 = (unsigned short*)alloc(16384);
  unsigned short* W0T2 = (unsigned short*)alloc(16384);
  unsigned short* WcT1 = (unsigned short*)alloc(65536);
  unsigned short* WcT2 = (unsigned short*)alloc(65536);
  unsigned short* WfT1 = (unsigned short*)alloc(163840);
  unsigned short* WfT2 = (unsigned short*)alloc(163840);
  unsigned short* webt1 = (unsigned short*)alloc(2048);
  unsigned short* webt2 = (unsigned short*)alloc(2048);
  unsigned short* eab1 = (unsigned short*)alloc(4194304);
  unsigned short* eab2 = (unsigned short*)alloc(4194304);
  int* meta1 = (int*)alloc(524288);
  int* meta2 = (int*)alloc(524288);
  int* perm1 = (int*)alloc(524288);
  int* perm2 = (int*)alloc(524288);
  (void)in_sizes; (void)n_in; (void)out_size; (void)ws_size;

  // ---- prep ----
  sort_edges_dual<<<512, 256, 0, stream>>>(ei1, ei2, meta1, meta2, perm1, perm2);
  transpose_all<<<3840, 256, 0, stream>>>(W0_1, W0_2, Wn1, Ws1, Wn2, Ws2,
                                          Wf1, Wf2, W0T1, W0T2, WcT1, WcT2,
                                          WfT1, WfT2);
  misc_prep<<<36, 256, 0, stream>>>(bm1, bs1, bm2, bs2, We1, We2,
                                    bcat1, bcat2, webt1, webt2);
  ea_gather_pack_dual<<<4096, 256, 0, stream>>>(ea1, ea2, perm1, perm2,
                                                eab1, eab2);

  // ---- embed: xm = rrelu(x @ W0 + b0) ----
  gemm_bf16_dual<<<dim3(128, 2, 2), 256, 0, stream>>>(
      x1, W0T1, b0_1, xmA1, x2, W0T2, b0_2, xmA2, 128, 256, 128, 2);

  // ---- 3 message-passing steps ----
  float* cur1 = xmA1; float* cur2 = xmA2;
  float* nxt1 = xmB1; float* nxt2 = xmB2;
  for (int step = 0; step < 3; ++step) {
    gemm_bf16_dual<<<dim3(128, 4, 2), 256, 0, stream>>>(
        cur1, WcT1, bcat1, y1, cur2, WcT2, bcat2, y2, 256, 512, 256, 0);
    edge_conv_dual<<<dim3(512, 1, 2), 512, 0, stream>>>(
        y1, meta1, eab1, webt1, nxt1,
        y2, meta2, eab2, webt2, nxt2);
    dot_pool_k<<<256, 256, 0, stream>>>(nxt1, nxt2, fusion, step);
    float* t1 = cur1; cur1 = nxt1; nxt1 = t1;
    float* t2 = cur2; cur2 = nxt2; nxt2 = t2;
  }

  // ---- readout + head ----
  readout_dual<<<512, 256, 0, stream>>>(cur1, cur2, R1, R2);
  gemm_bf16_dual<<<dim3(2, 2, 2), 256, 0, stream>>>(
      R1, WfT1, bf1, outm1, R2, WfT2, bf2, outm2, 1280, 256, 1280, 0);
  final_head<<<256, 256, 0, stream>>>(outm1, outm2, fusion,
                                      Wo1, bo1, Wo2, bo2, out);
}